// Round 1
// baseline (135.308 us; speedup 1.0000x reference)
//
#include <hip/hip_runtime.h>
#include <math.h>

#define EPS 1e-5f
#define B 64
#define N 1024
#define W 64
#define R 4
#define NW 1

__device__ __forceinline__ float softplus_f(float x) {
    return x > 0.f ? x + log1pf(expf(-x)) : log1pf(expf(x));
}

// -------------------- usage --------------------
__global__ void k_usage(const float* __restrict__ pww,
                        const float* __restrict__ fg,
                        const float* __restrict__ prw,
                        const float* __restrict__ pu,
                        float* __restrict__ usage) {
    int idx = blockIdx.x * blockDim.x + threadIdx.x;  // over B*N
    if (idx >= B * N) return;
    int b = idx >> 10;
    int n = idx & (N - 1);
    float wwp = 1.f;
    for (int h = 0; h < NW; ++h)
        wwp *= 1.f - pww[(b * NW + h) * N + n];
    float ww = 1.f - wwp;
    float pun = pu[idx];
    float u = pun + (1.f - pun) * ww;
    float phi = 1.f;
    for (int r = 0; r < R; ++r)
        phi *= 1.f - fg[b * R + r] * prw[(size_t)(b * R + r) * N + n];
    usage[idx] = u * phi;
}

// -------------------- allocation (sort per batch) --------------------
__global__ __launch_bounds__(1024) void k_alloc(const float* __restrict__ usage,
                                                float* __restrict__ alloc) {
    __shared__ float nu[N];
    __shared__ int   id[N];
    __shared__ float pp[N];
    int b = blockIdx.x;
    int t = threadIdx.x;

    float u = EPS + (1.f - EPS) * usage[(size_t)b * N + t];
    nu[t] = 1.f - u;   // nonusage
    id[t] = t;
    __syncthreads();

    // Bitonic sort: descending nonusage, ties broken by ascending original
    // index (matches stable jnp.argsort(-nonusage)).
    for (int k = 2; k <= N; k <<= 1) {
        for (int j = k >> 1; j > 0; j >>= 1) {
            int ixj = t ^ j;
            if (ixj > t) {
                float na = nu[t], nb = nu[ixj];
                int   ia = id[t], ib = id[ixj];
                bool a_first = (na > nb) || (na == nb && ia < ib);
                bool up = ((t & k) == 0);
                bool doSwap = up ? !a_first : a_first;
                if (doSwap) {
                    nu[t] = nb; nu[ixj] = na;
                    id[t] = ib; id[ixj] = ia;
                }
            }
            __syncthreads();
        }
    }

    // Inclusive prefix product of sorted_usage = 1 - sorted_nonusage.
    pp[t] = 1.f - nu[t];
    __syncthreads();
    for (int off = 1; off < N; off <<= 1) {
        float v = pp[t];
        float w = (t >= off) ? pp[t - off] : 1.f;
        __syncthreads();
        pp[t] = v * w;
        __syncthreads();
    }
    float excl = (t > 0) ? pp[t - 1] : 1.f;   // exclusive prefix product
    // Scatter: alloc[indices[k]] = sorted_alloc[k]
    alloc[(size_t)b * N + id[t]] = nu[t] * excl;
}

// -------------------- cosine scores (all 5 heads, one memory pass) ------
__global__ void k_scores(const float* __restrict__ memory,
                         const float* __restrict__ read_keys,
                         const float* __restrict__ read_strengths,
                         const float* __restrict__ write_keys,
                         const float* __restrict__ write_strengths,
                         float* __restrict__ out_rw,   // [B,R,N] sharpened acts
                         float* __restrict__ out_ww) { // [B,N] sharpened acts
    __shared__ float sk[5 * W];
    __shared__ float s_knorm[5];
    __shared__ float s_scale[5];
    int b = blockIdx.y;
    int t = threadIdx.x;   // 256

    for (int l = t; l < 5 * W; l += 256) {
        int h = l / W, w = l - h * W;
        sk[l] = (h < R) ? read_keys[((size_t)b * R + h) * W + w]
                        : write_keys[(size_t)b * W + w];
    }
    __syncthreads();
    if (t < 5) {
        float s = 0.f;
        for (int w = 0; w < W; ++w) s += sk[t * W + w] * sk[t * W + w];
        s_knorm[t] = sqrtf(s + EPS);
        float st = (t < R) ? read_strengths[b * R + t] : write_strengths[b];
        s_scale[t] = softplus_f(st);
    }
    __syncthreads();

    int n = blockIdx.x * 256 + t;
    const float4* mrow = (const float4*)(memory + ((size_t)b * N + n) * W);
    float dot[5] = {0.f, 0.f, 0.f, 0.f, 0.f};
    float msum = 0.f;
    for (int w4 = 0; w4 < W / 4; ++w4) {
        float4 m = mrow[w4];
        msum += m.x * m.x + m.y * m.y + m.z * m.z + m.w * m.w;
        for (int h = 0; h < 5; ++h) {
            dot[h] += sk[h * W + w4 * 4 + 0] * m.x + sk[h * W + w4 * 4 + 1] * m.y
                    + sk[h * W + w4 * 4 + 2] * m.z + sk[h * W + w4 * 4 + 3] * m.w;
        }
    }
    float mnorm = sqrtf(msum + EPS);
    for (int h = 0; h < 5; ++h) {
        float act = dot[h] / (s_knorm[h] * mnorm + EPS);
        float sharp = act * s_scale[h];
        if (h < R) out_rw[((size_t)b * R + h) * N + n] = sharp;
        else       out_ww[(size_t)b * N + n] = sharp;
    }
}

// -------------------- softmax over N, in place --------------------
__global__ void k_softmax(float* __restrict__ out_rw, float* __restrict__ out_ww) {
    int blk = blockIdx.x;     // B*5
    int b = blk / 5, h = blk - b * 5;
    float* p = (h < R) ? (out_rw + ((size_t)b * R + h) * N)
                       : (out_ww + (size_t)b * N);
    int t = threadIdx.x;      // 256
    float v[4];
    float mx = -INFINITY;
    for (int k = 0; k < 4; ++k) { v[k] = p[t + 256 * k]; mx = fmaxf(mx, v[k]); }
    __shared__ float red[256];
    red[t] = mx; __syncthreads();
    for (int s = 128; s > 0; s >>= 1) {
        if (t < s) red[t] = fmaxf(red[t], red[t + s]);
        __syncthreads();
    }
    mx = red[0]; __syncthreads();
    float sum = 0.f;
    for (int k = 0; k < 4; ++k) { v[k] = expf(v[k] - mx); sum += v[k]; }
    red[t] = sum; __syncthreads();
    for (int s = 128; s > 0; s >>= 1) {
        if (t < s) red[t] += red[t + s];
        __syncthreads();
    }
    float inv = 1.f / red[0];
    for (int k = 0; k < 4; ++k) p[t + 256 * k] = v[k] * inv;
}

// -------------------- final write weights + precedence --------------------
__global__ void k_wwprec(const float* __restrict__ alloc,
                         const float* __restrict__ alloc_gate,
                         const float* __restrict__ write_gate,
                         const float* __restrict__ prev_prec,
                         float* __restrict__ out_ww,   // in: content softmax, out: final ww
                         float* __restrict__ out_prec) {
    int b = blockIdx.x;
    int t = threadIdx.x;  // 256
    float ag = alloc_gate[b], wg = write_gate[b];
    float v[4];
    float sum = 0.f;
    for (int k = 0; k < 4; ++k) {
        int n = t + 256 * k;
        float c = out_ww[(size_t)b * N + n];
        float a = alloc[(size_t)b * N + n];
        float w = wg * (ag * a + (1.f - ag) * c);
        v[k] = w; sum += w;
    }
    __shared__ float red[256];
    red[t] = sum; __syncthreads();
    for (int s = 128; s > 0; s >>= 1) {
        if (t < s) red[t] += red[t + s];
        __syncthreads();
    }
    float wsum = red[0];
    for (int k = 0; k < 4; ++k) {
        int n = t + 256 * k;
        out_ww[(size_t)b * N + n] = v[k];
        out_prec[(size_t)b * N + n] = (1.f - wsum) * prev_prec[(size_t)b * N + n] + v[k];
    }
}

// -------------------- link update (the HBM-bound bulk) --------------------
__global__ void k_link(const float* __restrict__ ww,
                       const float* __restrict__ pprec,
                       const float* __restrict__ plink,
                       float* __restrict__ link) {
    int row = blockIdx.x;               // b*N + i
    int b = row >> 10, i = row & (N - 1);
    int t = threadIdx.x;                // 256 threads = 256 float4 = one row
    float wi = ww[row];
    size_t base4 = ((size_t)row << 10) >> 2;   // row*N/4 in float4 units
    float4 pl = ((const float4*)plink)[base4 + t];
    float4 wj = ((const float4*)(ww + (size_t)b * N))[t];
    float4 pj = ((const float4*)(pprec + (size_t)b * N))[t];
    float4 o;
    o.x = (1.f - wi - wj.x) * pl.x + wi * pj.x;
    o.y = (1.f - wi - wj.y) * pl.y + wi * pj.y;
    o.z = (1.f - wi - wj.z) * pl.z + wi * pj.z;
    o.w = (1.f - wi - wj.w) * pl.w + wi * pj.w;
    int j0 = t * 4;
    if (i >= j0 && i < j0 + 4) {       // zero the diagonal
        if      (i == j0)     o.x = 0.f;
        else if (i == j0 + 1) o.y = 0.f;
        else if (i == j0 + 2) o.z = 0.f;
        else                  o.w = 0.f;
    }
    ((float4*)link)[base4 + t] = o;
}

extern "C" void kernel_launch(void* const* d_in, const int* in_sizes, int n_in,
                              void* d_out, int out_size, void* d_ws, size_t ws_size,
                              hipStream_t stream) {
    const float* memory          = (const float*)d_in[0];
    const float* read_keys       = (const float*)d_in[1];
    const float* read_strengths  = (const float*)d_in[2];
    const float* write_keys      = (const float*)d_in[3];
    const float* write_strengths = (const float*)d_in[4];
    const float* free_gate       = (const float*)d_in[5];
    const float* alloc_gate      = (const float*)d_in[6];
    const float* write_gate      = (const float*)d_in[7];
    const float* prev_read_w     = (const float*)d_in[8];
    const float* prev_write_w    = (const float*)d_in[9];
    const float* prev_usage      = (const float*)d_in[10];
    const float* prev_link       = (const float*)d_in[11];
    const float* prev_prec       = (const float*)d_in[12];

    float* out = (float*)d_out;
    float* out_rw    = out;                           // [B,R,N]
    float* out_ww    = out_rw + (size_t)B * R * N;    // [B,NW,N]
    float* out_usage = out_ww + (size_t)B * NW * N;   // [B,N]
    float* out_link  = out_usage + (size_t)B * N;     // [B,NW,N,N]
    float* out_prec  = out_link + (size_t)B * NW * N * N; // [B,NW,N]

    // alloc scratch lives in the first B*N floats of out_link; k_link fully
    // overwrites that region afterwards, so this is race-free & deterministic.
    float* alloc_buf = out_link;

    k_usage<<<(B * N + 255) / 256, 256, 0, stream>>>(
        prev_write_w, free_gate, prev_read_w, prev_usage, out_usage);

    k_alloc<<<B, 1024, 0, stream>>>(out_usage, alloc_buf);

    dim3 g3(N / 256, B);
    k_scores<<<g3, 256, 0, stream>>>(memory, read_keys, read_strengths,
                                     write_keys, write_strengths, out_rw, out_ww);

    k_softmax<<<B * 5, 256, 0, stream>>>(out_rw, out_ww);

    k_wwprec<<<B, 256, 0, stream>>>(alloc_buf, alloc_gate, write_gate,
                                    prev_prec, out_ww, out_prec);

    k_link<<<B * N, 256, 0, stream>>>(out_ww, prev_prec, prev_link, out_link);
}